// Round 2
// 785.835 us; speedup vs baseline: 1.0171x; 1.0171x over previous
//
#include <hip/hip_runtime.h>
#include <hip/hip_bf16.h>

#define BS 2
#define NN 65536
#define CC 256
#define KNNK 16

typedef short bf16x8 __attribute__((ext_vector_type(8)));
typedef float f32x4 __attribute__((ext_vector_type(4)));
typedef int i32x4 __attribute__((ext_vector_type(4)));

__device__ __forceinline__ float bfu(unsigned short v) {
  return __builtin_bit_cast(float, ((unsigned)v) << 16);
}
__device__ __forceinline__ float bflo(unsigned u) { return __builtin_bit_cast(float, u << 16); }
__device__ __forceinline__ float bfhi(unsigned u) { return __builtin_bit_cast(float, u & 0xFFFF0000u); }

// async global->LDS, 16B per lane; LDS dest = wave-uniform base + lane*16
__device__ __forceinline__ void gl16(const void* g, void* l) {
  __builtin_amdgcn_global_load_lds((const __attribute__((address_space(1))) void*)g,
                                   (__attribute__((address_space(3))) void*)l, 16, 0, 0);
}

// 2x fp32 -> packed 2x bf16 (RNE) via v_cvt_pk_bf16_f32
__device__ __forceinline__ int pk2(float a, float b) {
  union { __hip_bfloat162 h; int i; } u;
  u.h = __float22bfloat162_rn(make_float2(a, b));
  return u.i;
}
// 8x fp32 -> bf16x8
__device__ __forceinline__ bf16x8 cvt8(f32x4 a, f32x4 b) {
  i32x4 p;
  p[0] = pk2(a[0], a[1]);
  p[1] = pk2(a[2], a[3]);
  p[2] = pk2(b[0], b[1]);
  p[3] = pk2(b[2], b[3]);
  return __builtin_bit_cast(bf16x8, p);
}
__device__ __forceinline__ unsigned short f2b(float f) {
  union { __hip_bfloat16 h; unsigned short s; } u;
  u.h = __float2bfloat16(f);
  return u.s;
}

// ---- W fp32 -> bf16, all three matrices. dst = scratch in d_out. ----
__global__ __launch_bounds__(256)
void convw_kernel(const float* __restrict__ Wq, const float* __restrict__ Wk,
                  const float* __restrict__ Wv, unsigned short* __restrict__ W16) {
  const float* src = (blockIdx.y == 0) ? Wq : (blockIdx.y == 1) ? Wk : Wv;
  unsigned short* dst = W16 + blockIdx.y * 65536;
  const int i = (blockIdx.x * 256 + threadIdx.x) * 4;
  float4 v = *(const float4*)(src + i);
  *(int2*)(dst + i) = make_int2(pk2(v.x, v.y), pk2(v.z, v.w));
}

// ---- fused 3x projection: out[m][n] = sum_k A[m][k]*W[n][k] + bias[n] ----
// BM=64, BN=256(full), BK=32. A staged fp32 via global_load_lds with XOR-swizzled
// source (read-side chunk c -> c^(row&7) spreads b128 reads over all 32 banks).
// W pre-converted bf16: 64B row stride is naturally conflict-free. cvt on A read.
__global__ __launch_bounds__(256)
void proj3_kernel(const float* __restrict__ Qin, const float* __restrict__ Kin,
                  const float* __restrict__ Vin, const unsigned short* __restrict__ W16,
                  const float* __restrict__ Qb, const float* __restrict__ Kb,
                  const float* __restrict__ Vb,
                  float* __restrict__ Qp, unsigned short* __restrict__ Kp,
                  unsigned short* __restrict__ Vp) {
  constexpr int BK = 32;
  __shared__ __align__(16) float As[64 * BK];            // 8 KB
  __shared__ __align__(16) unsigned short Bsh[256 * BK]; // 16 KB

  const int z = blockIdx.y;
  const float* A = (z == 0) ? Qin : (z == 1) ? Kin : Vin;
  const unsigned short* W = W16 + z * 65536;
  const float* bias = (z == 0) ? Qb : (z == 1) ? Kb : Vb;

  const int t = threadIdx.x;
  const int w = t >> 6, l = t & 63;
  const int lrow = l & 15, quad = l >> 4;
  const int wm = w >> 1, wn = w & 1;  // wave tile: 32 rows x 128 cols
  const long row0 = (long)blockIdx.x * 64;

  // staging sources (per-lane). A: wave w stages rows w*16..w*16+15 (2 loads of 8 rows),
  // source chunk = ldschunk ^ (row&7) (inverse of read-side swizzle).
  const float* aS = A + (row0 + w * 16 + (l >> 3)) * 256 + (((l & 7) ^ (l >> 3)) << 2);
  // B: wave w stages rows w*64..w*64+63 (4 loads of 16 rows), linear.
  const unsigned short* bS = W + (w * 64 + (l >> 2)) * 256 + ((l & 3) << 3);
  float* ldsA0 = &As[(w * 16) * BK];
  float* ldsA1 = &As[(w * 16 + 8) * BK];
  unsigned short* ldsB0 = &Bsh[(w * 64) * BK];

  // fragment read addresses
  const int xA = lrow & 7;
  const float* ra0 = &As[(wm * 32 + lrow) * BK + (((2 * quad) ^ xA) << 2)];
  const float* ra1 = &As[(wm * 32 + lrow) * BK + (((2 * quad + 1) ^ xA) << 2)];
  const unsigned short* rb = &Bsh[(wn * 128 + lrow) * BK + quad * 8];

  f32x4 acc[2][8];
#pragma unroll
  for (int i = 0; i < 2; ++i)
#pragma unroll
    for (int j = 0; j < 8; ++j) acc[i][j] = f32x4{0.f, 0.f, 0.f, 0.f};

  for (int k0 = 0; k0 < 256; k0 += BK) {
    gl16(aS + k0, ldsA0);
    gl16(aS + k0 + 8 * 256, ldsA1);
    gl16(bS + k0, ldsB0);
    gl16(bS + k0 + 1 * 16 * 256, ldsB0 + 1 * 16 * BK);
    gl16(bS + k0 + 2 * 16 * 256, ldsB0 + 2 * 16 * BK);
    gl16(bS + k0 + 3 * 16 * 256, ldsB0 + 3 * 16 * BK);
    __syncthreads();  // drains vmcnt(0): staged data visible
    bf16x8 af[2], bfr[8];
#pragma unroll
    for (int mi = 0; mi < 2; ++mi) {
      f32x4 f0 = *(const f32x4*)(ra0 + mi * 16 * BK);
      f32x4 f1 = *(const f32x4*)(ra1 + mi * 16 * BK);
      af[mi] = cvt8(f0, f1);
    }
#pragma unroll
    for (int ni = 0; ni < 8; ++ni) bfr[ni] = *(const bf16x8*)(rb + ni * 16 * BK);
#pragma unroll
    for (int mi = 0; mi < 2; ++mi)
#pragma unroll
      for (int ni = 0; ni < 8; ++ni)
        acc[mi][ni] = __builtin_amdgcn_mfma_f32_16x16x32_bf16(af[mi], bfr[ni], acc[mi][ni], 0, 0, 0);
    __syncthreads();  // compute done before next-iter overwrite
  }

  // C/D layout: col = lane&15, row = quad*4 + reg (m89-verified)
#pragma unroll
  for (int mi = 0; mi < 2; ++mi)
#pragma unroll
    for (int ni = 0; ni < 8; ++ni) {
      const long gr0 = row0 + wm * 32 + mi * 16 + quad * 4;
      const int gc = wn * 128 + ni * 16 + lrow;
      const float bv = bias[gc];
      if (z == 0) {
#pragma unroll
        for (int r = 0; r < 4; ++r) Qp[(gr0 + r) * 256 + gc] = acc[mi][ni][r] + bv;
      } else {
        unsigned short* O = (z == 1) ? Kp : Vp;
#pragma unroll
        for (int r = 0; r < 4; ++r) O[(gr0 + r) * 256 + gc] = f2b(acc[mi][ni][r] + bv);
      }
    }
}

// One 256-thread block per (b, n). Softmax computed ONCE by lanes 0-15 (was
// replicated 256x = 4096 exp per token -> now 16), weights broadcast via LDS.
__global__ __launch_bounds__(256)
void attn_kernel(const float* __restrict__ Qp, const unsigned short* __restrict__ Kp,
                 const unsigned short* __restrict__ Vp, const int* __restrict__ knn,
                 const float* __restrict__ ln_g, const float* __restrict__ ln_b,
                 float* __restrict__ out) {
  const int n = blockIdx.x, b = blockIdx.y, t = threadIdx.x;
  __shared__ int sidx[KNNK];
  __shared__ float sdots[KNNK];
  __shared__ float sw[KNNK];
  __shared__ float sred[8];
  if (t < KNNK) sidx[t] = knn[n * KNNK + t];
  __syncthreads();

  const long base = ((long)b * NN + n) * CC;
  const long kbase = (long)b * NN * CC;
  int nbr[KNNK];
#pragma unroll
  for (int i = 0; i < KNNK; ++i) nbr[i] = sidx[i];

  // ---- QK^T dot for neighbor k over this thread's 16 channels ----
  const int k = t >> 4, cg = t & 15;
  {
    const float* qp = Qp + base + cg * 16;
    float4 q0 = *(const float4*)(qp);
    float4 q1 = *(const float4*)(qp + 4);
    float4 q2 = *(const float4*)(qp + 8);
    float4 q3 = *(const float4*)(qp + 12);
    const unsigned short* kr = Kp + kbase + (long)nbr[k] * CC + cg * 16;
    int4 kv0 = *(const int4*)(kr);
    int4 kv1 = *(const int4*)(kr + 8);
    float p = q0.x * bflo(kv0.x) + q0.y * bfhi(kv0.x)
            + q0.z * bflo(kv0.y) + q0.w * bfhi(kv0.y)
            + q1.x * bflo(kv0.z) + q1.y * bfhi(kv0.z)
            + q1.z * bflo(kv0.w) + q1.w * bfhi(kv0.w)
            + q2.x * bflo(kv1.x) + q2.y * bfhi(kv1.x)
            + q2.z * bflo(kv1.y) + q2.w * bfhi(kv1.y)
            + q3.x * bflo(kv1.z) + q3.y * bfhi(kv1.z)
            + q3.z * bflo(kv1.w) + q3.w * bfhi(kv1.w);
#pragma unroll
    for (int m = 1; m < 16; m <<= 1) p += __shfl_xor(p, m);
    if (cg == 0) sdots[k] = p * 0.0625f;  // 1/sqrt(256)
  }
  __syncthreads();

  // ---- softmax once: lanes 0-15 of wave 0 ----
  if (t < KNNK) {
    float v = sdots[t];
    float mx = v;
#pragma unroll
    for (int m = 1; m < 16; m <<= 1) mx = fmaxf(mx, __shfl_xor(mx, m));
    float e = __expf(v - mx);
    float s = e;
#pragma unroll
    for (int m = 1; m < 16; m <<= 1) s += __shfl_xor(s, m);
    sw[t] = e / s;  // normalized weight
  }
  __syncthreads();

  // ---- weighted V sum: thread = channel t (sw reads are LDS broadcasts) ----
  float wgt[KNNK];
#pragma unroll
  for (int i = 0; i < KNNK; ++i) wgt[i] = sw[i];
  float o = 0.f;
#pragma unroll
  for (int i = 0; i < KNNK; ++i)
    o += wgt[i] * bfu(Vp[kbase + (long)nbr[i] * CC + t]);
  o += Qp[base + t];  // residual (fp32)

  // ---- LayerNorm over 256 channels ----
  float s1 = o, s2 = o * o;
#pragma unroll
  for (int m = 1; m < 64; m <<= 1) {
    s1 += __shfl_xor(s1, m);
    s2 += __shfl_xor(s2, m);
  }
  const int wv = t >> 6;
  if ((t & 63) == 0) { sred[wv] = s1; sred[wv + 4] = s2; }
  __syncthreads();
  const float S1 = sred[0] + sred[1] + sred[2] + sred[3];
  const float S2 = sred[4] + sred[5] + sred[6] + sred[7];
  const float mu = S1 * (1.0f / 256.0f);
  const float var = S2 * (1.0f / 256.0f) - mu * mu;
  const float rs = rsqrtf(var + 1e-5f);
  out[base + t] = (o - mu) * rs * ln_g[t] + ln_b[t];
}

extern "C" void kernel_launch(void* const* d_in, const int* in_sizes, int n_in,
                              void* d_out, int out_size, void* d_ws, size_t ws_size,
                              hipStream_t stream) {
  const float* Q   = (const float*)d_in[0];
  const float* K   = (const float*)d_in[1];
  const float* V   = (const float*)d_in[2];
  const int*   knn = (const int*)d_in[3];
  const float* Wq  = (const float*)d_in[4];
  const float* Wqb = (const float*)d_in[5];
  const float* Wk  = (const float*)d_in[6];
  const float* Wkb = (const float*)d_in[7];
  const float* Wv  = (const float*)d_in[8];
  const float* Wvb = (const float*)d_in[9];
  const float* ln_g = (const float*)d_in[10];
  const float* ln_b = (const float*)d_in[11];
  float* out = (float*)d_out;

  // workspace: Qp fp32 (134.2 MB) | Kp bf16 (67.1 MB) | Vp bf16 (67.1 MB)
  float* Qp = (float*)d_ws;
  unsigned short* Kp = (unsigned short*)((char*)d_ws + (size_t)BS * NN * CC * 4);
  unsigned short* Vp = Kp + (size_t)BS * NN * CC;
  // W16 scratch (384 KB) lives at the head of d_out — dead until attn overwrites.
  unsigned short* W16 = (unsigned short*)d_out;

  convw_kernel<<<dim3(64, 3), 256, 0, stream>>>(Wq, Wk, Wv, W16);
  proj3_kernel<<<dim3(2048, 3), 256, 0, stream>>>(Q, K, V, W16, Wqb, Wkb, Wvb, Qp, Kp, Vp);
  attn_kernel<<<dim3(NN, BS), 256, 0, stream>>>(Qp, Kp, Vp, knn, ln_g, ln_b, out);
}